// Round 1
// baseline (959.581 us; speedup 1.0000x reference)
//
#include <hip/hip_runtime.h>
#include <math.h>

#define NRAYS 8192
#define NSAMP 128
#define RAYS_PER_BLOCK 2
#define ASTRIDE 68   // dwords per-thread LDS activation row (64 + 4 pad), 272B (16B aligned)

__device__ __forceinline__ float softplusf_(float x){ return (x > 20.f) ? x : log1pf(expf(x)); }
__device__ __forceinline__ float sigmoidf_(float x){ return 1.f / (1.f + expf(-x)); }

// y[64] = x[K] @ W(K x 64) + b ; input x from per-thread LDS row, acc in regs.
template<int K>
__device__ __forceinline__ void fc64(const float* __restrict__ W,
                                     const float* __restrict__ b,
                                     const float* actIn, float4 acc[16])
{
#pragma unroll
  for (int j = 0; j < 16; ++j) acc[j] = ((const float4*)b)[j];
#pragma unroll 2
  for (int i4 = 0; i4 < K / 4; ++i4) {
    float4 x = *(const float4*)(actIn + i4 * 4);
    const float* Wb = W + i4 * 4 * 64;
#pragma unroll
    for (int j = 0; j < 16; ++j) {
      float4 w0 = ((const float4*)(Wb      ))[j];
      float4 w1 = ((const float4*)(Wb + 64 ))[j];
      float4 w2 = ((const float4*)(Wb + 128))[j];
      float4 w3 = ((const float4*)(Wb + 192))[j];
      acc[j].x = fmaf(x.w, w3.x, fmaf(x.z, w2.x, fmaf(x.y, w1.x, fmaf(x.x, w0.x, acc[j].x))));
      acc[j].y = fmaf(x.w, w3.y, fmaf(x.z, w2.y, fmaf(x.y, w1.y, fmaf(x.x, w0.y, acc[j].y))));
      acc[j].z = fmaf(x.w, w3.z, fmaf(x.z, w2.z, fmaf(x.y, w1.z, fmaf(x.x, w0.z, acc[j].z))));
      acc[j].w = fmaf(x.w, w3.w, fmaf(x.z, w2.w, fmaf(x.y, w1.w, fmaf(x.x, w0.w, acc[j].w))));
    }
  }
}

extern "C" __global__ __launch_bounds__(256, 2)
void lightplane_fwd(const float* __restrict__ origins, const float* __restrict__ dirs,
                    const float* __restrict__ nearv,   const float* __restrict__ farv,
                    const float* __restrict__ grid,
                    const float* __restrict__ Wr,  const float* __restrict__ br,
                    const float* __restrict__ Wt1, const float* __restrict__ bt1,
                    const float* __restrict__ Wt2, const float* __restrict__ bt2,
                    const float* __restrict__ Wo1, const float* __restrict__ bo1,
                    const float* __restrict__ Wo2, const float* __restrict__ bo2,
                    const float* __restrict__ Wc1, const float* __restrict__ bc1,
                    const float* __restrict__ Wc2, const float* __restrict__ bc2,
                    float* __restrict__ out)
{
  __shared__ float s_act[256 * ASTRIDE];                    // 69632 B
  __shared__ float s_scan[RAYS_PER_BLOCK][NSAMP];           // 1024 B
  __shared__ float s_enc[RAYS_PER_BLOCK][64];               // 512 B
  __shared__ float s_part[RAYS_PER_BLOCK][2][4];            // 64 B

  const int tid   = threadIdx.x;
  const int r_loc = tid >> 7;        // 0..1
  const int s_idx = tid & 127;       // sample within ray
  const int ray   = blockIdx.x * RAYS_PER_BLOCK + r_loc;

  // ---- per-ray harmonic encoding @ Wr + br (threads 0..127: (ray, out-neuron)) ----
  if (tid < RAYS_PER_BLOCK * 64) {
    const int rr = tid >> 6, j = tid & 63;
    const int rg = blockIdx.x * RAYS_PER_BLOCK + rr;
    const float ddx = dirs[rg * 3 + 0], ddy = dirs[rg * 3 + 1], ddz = dirs[rg * 3 + 2];
    float h[21];
    float f = 1.f;
#pragma unroll
    for (int q = 0; q < 3; ++q) {
      h[q * 3 + 0] = sinf(ddx * f); h[q * 3 + 1] = sinf(ddy * f); h[q * 3 + 2] = sinf(ddz * f);
      h[9 + q * 3 + 0] = cosf(ddx * f); h[9 + q * 3 + 1] = cosf(ddy * f); h[9 + q * 3 + 2] = cosf(ddz * f);
      f *= 2.f;
    }
    h[18] = ddx; h[19] = ddy; h[20] = ddz;
    float a = br[j];
#pragma unroll
    for (int i = 0; i < 21; ++i) a = fmaf(h[i], Wr[i * 64 + j], a);
    s_enc[rr][j] = a;
  }

  // ---- sample point ----
  const float dx = dirs[ray * 3 + 0], dy = dirs[ray * 3 + 1], dz = dirs[ray * 3 + 2];
  const float ox = origins[ray * 3 + 0], oy = origins[ray * 3 + 1], oz = origins[ray * 3 + 2];
  const float nr = nearv[ray], fa = farv[ray];
  const float t  = nr + (fa - nr) * ((s_idx + 0.5f) * (1.0f / 128.0f));
  const float px = fmaf(t, dx, ox), py = fmaf(t, dy, oy), pz = fmaf(t, dz, oz);

  // ---- trilinear gather (fp32) ----
  const float cx = (px + 1.f) * 63.5f, cy = (py + 1.f) * 63.5f, cz = (pz + 1.f) * 63.5f;
  const float fx0 = floorf(cx), fy0 = floorf(cy), fz0 = floorf(cz);
  const float frx = cx - fx0, fry = cy - fy0, frz = cz - fz0;
  int ix0 = min(max((int)fx0, 0), 127), iy0 = min(max((int)fy0, 0), 127), iz0 = min(max((int)fz0, 0), 127);
  int ix1 = min(ix0 + 1, 127), iy1 = min(iy0 + 1, 127), iz1 = min(iz0 + 1, 127);
  const float wxs[2] = {1.f - frx, frx}, wys[2] = {1.f - fry, fry}, wzs[2] = {1.f - frz, frz};
  const int xi[2] = {ix0, ix1}, yi[2] = {iy0, iy1}, zi[2] = {iz0, iz1};

  float4 fe[8];
#pragma unroll
  for (int k = 0; k < 8; ++k) fe[k] = make_float4(0.f, 0.f, 0.f, 0.f);
#pragma unroll
  for (int a = 0; a < 2; ++a) {
#pragma unroll
    for (int b2 = 0; b2 < 2; ++b2) {
#pragma unroll
      for (int c2 = 0; c2 < 2; ++c2) {
        const float wgt = wzs[a] * wys[b2] * wxs[c2];
        const float4* g4 = (const float4*)(grid + ((size_t)((zi[a] * 128 + yi[b2]) * 128 + xi[c2])) * 32);
#pragma unroll
        for (int k = 0; k < 8; ++k) {
          float4 g = g4[k];
          fe[k].x = fmaf(wgt, g.x, fe[k].x);
          fe[k].y = fmaf(wgt, g.y, fe[k].y);
          fe[k].z = fmaf(wgt, g.z, fe[k].z);
          fe[k].w = fmaf(wgt, g.w, fe[k].w);
        }
      }
    }
  }

  float* act = &s_act[tid * ASTRIDE];
#pragma unroll
  for (int k = 0; k < 8; ++k) *(float4*)(act + k * 4) = fe[k];

  float4 acc[16];

  // trunk layer 1: 32 -> 64, relu, store
  fc64<32>(Wt1, bt1, act, acc);
#pragma unroll
  for (int j = 0; j < 16; ++j) {
    float4 v = acc[j];
    v.x = fmaxf(v.x, 0.f); v.y = fmaxf(v.y, 0.f); v.z = fmaxf(v.z, 0.f); v.w = fmaxf(v.w, 0.f);
    *(float4*)(act + j * 4) = v;
  }
  // trunk layer 2: 64 -> 64, relu, store (this is `e`)
  fc64<64>(Wt2, bt2, act, acc);
#pragma unroll
  for (int j = 0; j < 16; ++j) {
    float4 v = acc[j];
    v.x = fmaxf(v.x, 0.f); v.y = fmaxf(v.y, 0.f); v.z = fmaxf(v.z, 0.f); v.w = fmaxf(v.w, 0.f);
    *(float4*)(act + j * 4) = v;
  }

  // opacity branch: relu(e@Wo1+bo1) @ Wo2 + bo2 (keep o in regs only)
  fc64<64>(Wo1, bo1, act, acc);
  float raw = bo2[0];
#pragma unroll
  for (int j = 0; j < 16; ++j) {
    float4 v = acc[j];
    float4 w = ((const float4*)Wo2)[j];
    raw += fmaxf(v.x, 0.f) * w.x + fmaxf(v.y, 0.f) * w.y + fmaxf(v.z, 0.f) * w.z + fmaxf(v.w, 0.f) * w.w;
  }
  const float density = softplusf_(raw);
  const float delta   = (fa - nr) * (1.0f / 128.0f);
  const float alpha   = 1.f - expf(-delta * density);

  // color branch: cin = e + ray_enc (in place), then 64->64 relu, 64->3, sigmoid
  __syncthreads();   // s_enc ready
#pragma unroll
  for (int j = 0; j < 16; ++j) {
    float4 e = *(const float4*)(act + j * 4);
    float4 en = ((const float4*)&s_enc[r_loc][0])[j];
    e.x += en.x; e.y += en.y; e.z += en.z; e.w += en.w;
    *(float4*)(act + j * 4) = e;
  }
  fc64<64>(Wc1, bc1, act, acc);
  float c0 = bc2[0], c1 = bc2[1], c2 = bc2[2];
#pragma unroll
  for (int j = 0; j < 16; ++j) {
    const float hv[4] = {fmaxf(acc[j].x, 0.f), fmaxf(acc[j].y, 0.f), fmaxf(acc[j].z, 0.f), fmaxf(acc[j].w, 0.f)};
#pragma unroll
    for (int l = 0; l < 4; ++l) {
      const int jj = j * 4 + l;
      c0 = fmaf(hv[l], Wc2[jj * 3 + 0], c0);
      c1 = fmaf(hv[l], Wc2[jj * 3 + 1], c1);
      c2 = fmaf(hv[l], Wc2[jj * 3 + 2], c2);
    }
  }
  c0 = sigmoidf_(c0); c1 = sigmoidf_(c1); c2 = sigmoidf_(c2);

  // ---- transmittance: inclusive product scan of (1-alpha) over the ray ----
  float v = 1.f - alpha;
  s_scan[r_loc][s_idx] = v;
  __syncthreads();
#pragma unroll
  for (int off = 1; off < 128; off <<= 1) {
    const float u = (s_idx >= off) ? s_scan[r_loc][s_idx - off] : 1.f;
    __syncthreads();
    v *= u;
    s_scan[r_loc][s_idx] = v;
    __syncthreads();
  }
  const float Texcl = (s_idx == 0) ? 1.f : s_scan[r_loc][s_idx - 1];
  const float w = Texcl * alpha;

  // ---- color integral: wave reduce then combine 2 waves/ray ----
  float p0 = w * c0, p1 = w * c1, p2 = w * c2;
#pragma unroll
  for (int off = 32; off > 0; off >>= 1) {
    p0 += __shfl_down(p0, off, 64);
    p1 += __shfl_down(p1, off, 64);
    p2 += __shfl_down(p2, off, 64);
  }
  if ((tid & 63) == 0) {
    const int wv = s_idx >> 6;
    s_part[r_loc][wv][0] = p0; s_part[r_loc][wv][1] = p1; s_part[r_loc][wv][2] = p2;
  }
  __syncthreads();
  if (s_idx == 0) {
    out[ray * 3 + 0] = s_part[r_loc][0][0] + s_part[r_loc][1][0];
    out[ray * 3 + 1] = s_part[r_loc][0][1] + s_part[r_loc][1][1];
    out[ray * 3 + 2] = s_part[r_loc][0][2] + s_part[r_loc][1][2];
    out[NRAYS * 3 + ray] = 1.f - s_scan[r_loc][127];
  }
}

extern "C" void kernel_launch(void* const* d_in, const int* in_sizes, int n_in,
                              void* d_out, int out_size, void* d_ws, size_t ws_size,
                              hipStream_t stream)
{
  (void)in_sizes; (void)n_in; (void)out_size; (void)d_ws; (void)ws_size;
  const float* origins = (const float*)d_in[0];
  const float* dirs    = (const float*)d_in[1];
  const float* nearv   = (const float*)d_in[2];
  const float* farv    = (const float*)d_in[3];
  const float* grid    = (const float*)d_in[4];
  const float* Wr  = (const float*)d_in[5];
  const float* br  = (const float*)d_in[6];
  const float* Wt1 = (const float*)d_in[7];
  const float* bt1 = (const float*)d_in[8];
  const float* Wt2 = (const float*)d_in[9];
  const float* bt2 = (const float*)d_in[10];
  const float* Wo1 = (const float*)d_in[11];
  const float* bo1 = (const float*)d_in[12];
  const float* Wo2 = (const float*)d_in[13];
  const float* bo2 = (const float*)d_in[14];
  const float* Wc1 = (const float*)d_in[15];
  const float* bc1 = (const float*)d_in[16];
  const float* Wc2 = (const float*)d_in[17];
  const float* bc2 = (const float*)d_in[18];
  float* out = (float*)d_out;

  dim3 g(NRAYS / RAYS_PER_BLOCK), b(256);
  lightplane_fwd<<<g, b, 0, stream>>>(origins, dirs, nearv, farv, grid,
                                      Wr, br, Wt1, bt1, Wt2, bt2, Wo1, bo1,
                                      Wo2, bo2, Wc1, bc1, Wc2, bc2, out);
}

// Round 2
// 507.857 us; speedup vs baseline: 1.8895x; 1.8895x over previous
//
#include <hip/hip_runtime.h>
#include <math.h>

#define NRAYS 8192
#define XPAD 72   // bf16 per LDS activation row: 64 + 8 pad (144 B, 16B-aligned, 2-way banks)

typedef short s16x8 __attribute__((ext_vector_type(8)));
typedef float f32x4 __attribute__((ext_vector_type(4)));

__device__ __forceinline__ unsigned short f2bf(float x){
  unsigned u = __float_as_uint(x);
  u += 0x7FFF + ((u >> 16) & 1);           // RNE
  return (unsigned short)(u >> 16);
}
__device__ __forceinline__ float bf2f(unsigned short s){ return __uint_as_float(((unsigned)s) << 16); }
__device__ __forceinline__ float softplusf_(float x){ return (x > 20.f) ? x : log1pf(expf(x)); }
__device__ __forceinline__ float sigmoidf_(float x){ return 1.f / (1.f + expf(-x)); }

// d_ws layout (ushort elements): WT1[64][32] @0, WT2[64][64] @2048, WO1[64][64] @6144, WC1[64][64] @10240
__global__ void prep_weights(const float* __restrict__ Wt1, const float* __restrict__ Wt2,
                             const float* __restrict__ Wo1, const float* __restrict__ Wc1,
                             unsigned short* __restrict__ ws)
{
  const int i0 = blockIdx.x * blockDim.x + threadIdx.x;
  const int st = gridDim.x * blockDim.x;
  for (int i = i0; i < 2048; i += st){ int n = i >> 5, k = i & 31; ws[i]         = f2bf(Wt1[k * 64 + n]); }
  for (int i = i0; i < 4096; i += st){ int n = i >> 6, k = i & 63; ws[2048 + i]  = f2bf(Wt2[k * 64 + n]); }
  for (int i = i0; i < 4096; i += st){ int n = i >> 6, k = i & 63; ws[6144 + i]  = f2bf(Wo1[k * 64 + n]); }
  for (int i = i0; i < 4096; i += st){ int n = i >> 6, k = i & 63; ws[10240 + i] = f2bf(Wc1[k * 64 + n]); }
}

// K=64 layer: acc[mt][nt] = bias + A @ W. A frags a[mt][ks]; WT[n][k] bf16 rows of 64.
__device__ __forceinline__ void layer64(const s16x8 a[4][2], const unsigned short* __restrict__ wt,
                                        const float* __restrict__ bias, int ln15, int quad,
                                        f32x4 acc[4][4])
{
  float bv[4];
#pragma unroll
  for (int nt = 0; nt < 4; ++nt) bv[nt] = bias[nt * 16 + ln15];
#pragma unroll
  for (int mt = 0; mt < 4; ++mt)
#pragma unroll
    for (int nt = 0; nt < 4; ++nt){ f32x4 c; c[0] = bv[nt]; c[1] = bv[nt]; c[2] = bv[nt]; c[3] = bv[nt]; acc[mt][nt] = c; }
#pragma unroll
  for (int ks = 0; ks < 2; ++ks){
    s16x8 b[4];
#pragma unroll
    for (int nt = 0; nt < 4; ++nt)
      b[nt] = *(const s16x8*)(wt + (nt * 16 + ln15) * 64 + ks * 32 + quad * 8);
#pragma unroll
    for (int mt = 0; mt < 4; ++mt)
#pragma unroll
      for (int nt = 0; nt < 4; ++nt)
        acc[mt][nt] = __builtin_amdgcn_mfma_f32_16x16x32_bf16(a[mt][ks], b[nt], acc[mt][nt], 0, 0, 0);
  }
}

// relu + bf16 + scatter D tiles back to X rows (wave-local rows)
__device__ __forceinline__ void store_relu(unsigned short* __restrict__ sX, int wrow, int ln15, int quad,
                                           const f32x4 acc[4][4])
{
#pragma unroll
  for (int mt = 0; mt < 4; ++mt){
    const int rowb = wrow + mt * 16 + quad * 4;
#pragma unroll
    for (int nt = 0; nt < 4; ++nt){
      const int col = nt * 16 + ln15;
#pragma unroll
      for (int r = 0; r < 4; ++r)
        sX[(rowb + r) * XPAD + col] = f2bf(fmaxf(acc[mt][nt][r], 0.f));
    }
  }
}

extern "C" __global__ __launch_bounds__(256, 2)
void lightplane_fwd(const float* __restrict__ origins, const float* __restrict__ dirs,
                    const float* __restrict__ nearv,   const float* __restrict__ farv,
                    const float* __restrict__ grid,
                    const float* __restrict__ Wr,  const float* __restrict__ br,
                    const float* __restrict__ bt1, const float* __restrict__ bt2,
                    const float* __restrict__ bo1,
                    const float* __restrict__ Wo2, const float* __restrict__ bo2,
                    const float* __restrict__ bc1,
                    const float* __restrict__ Wc2, const float* __restrict__ bc2,
                    const unsigned short* __restrict__ ws,
                    float* __restrict__ out)
{
  __shared__ unsigned short s_X[256 * XPAD];   // 36864 B
  __shared__ float s_scan[2][128];
  __shared__ float s_enc[2][64];
  __shared__ float s_part[2][2][4];

  const int tid   = threadIdx.x;
  const int lane  = tid & 63;
  const int wv    = tid >> 6;
  const int ln15  = lane & 15, quad = lane >> 4;
  const int wrow  = wv * 64;
  const int r_loc = tid >> 7;
  const int s_idx = tid & 127;
  const int ray   = blockIdx.x * 2 + r_loc;

  // ---- per-ray harmonic encoding @ Wr + br (f32, threads 0..127) ----
  if (tid < 128) {
    const int rr = tid >> 6, j = tid & 63;
    const int rg = blockIdx.x * 2 + rr;
    const float ddx = dirs[rg * 3 + 0], ddy = dirs[rg * 3 + 1], ddz = dirs[rg * 3 + 2];
    float h[21]; float f = 1.f;
#pragma unroll
    for (int q = 0; q < 3; ++q) {
      h[q * 3 + 0] = sinf(ddx * f); h[q * 3 + 1] = sinf(ddy * f); h[q * 3 + 2] = sinf(ddz * f);
      h[9 + q * 3 + 0] = cosf(ddx * f); h[9 + q * 3 + 1] = cosf(ddy * f); h[9 + q * 3 + 2] = cosf(ddz * f);
      f *= 2.f;
    }
    h[18] = ddx; h[19] = ddy; h[20] = ddz;
    float a = br[j];
#pragma unroll
    for (int i = 0; i < 21; ++i) a = fmaf(h[i], Wr[i * 64 + j], a);
    s_enc[rr][j] = a;
  }

  // ---- sample point + trilinear gather (fp32) ----
  const float dx = dirs[ray * 3 + 0], dy = dirs[ray * 3 + 1], dz = dirs[ray * 3 + 2];
  const float ox = origins[ray * 3 + 0], oy = origins[ray * 3 + 1], oz = origins[ray * 3 + 2];
  const float nr = nearv[ray], fa = farv[ray];
  const float t  = nr + (fa - nr) * ((s_idx + 0.5f) * (1.0f / 128.0f));
  const float px = fmaf(t, dx, ox), py = fmaf(t, dy, oy), pz = fmaf(t, dz, oz);

  const float cx = (px + 1.f) * 63.5f, cy = (py + 1.f) * 63.5f, cz = (pz + 1.f) * 63.5f;
  const float fx0 = floorf(cx), fy0 = floorf(cy), fz0 = floorf(cz);
  const float frx = cx - fx0, fry = cy - fy0, frz = cz - fz0;
  int ix0 = min(max((int)fx0, 0), 127), iy0 = min(max((int)fy0, 0), 127), iz0 = min(max((int)fz0, 0), 127);
  int ix1 = min(ix0 + 1, 127), iy1 = min(iy0 + 1, 127), iz1 = min(iz0 + 1, 127);
  const float wxs[2] = {1.f - frx, frx}, wys[2] = {1.f - fry, fry}, wzs[2] = {1.f - frz, frz};
  const int xi[2] = {ix0, ix1}, yi[2] = {iy0, iy1}, zi[2] = {iz0, iz1};

  float fe[32];
#pragma unroll
  for (int k = 0; k < 32; ++k) fe[k] = 0.f;
#pragma unroll
  for (int a = 0; a < 2; ++a)
#pragma unroll
    for (int b2 = 0; b2 < 2; ++b2)
#pragma unroll
      for (int c2 = 0; c2 < 2; ++c2) {
        const float wgt = wzs[a] * wys[b2] * wxs[c2];
        const float4* g4 = (const float4*)(grid + ((size_t)((zi[a] * 128 + yi[b2]) * 128 + xi[c2])) * 32);
#pragma unroll
        for (int k = 0; k < 8; ++k) {
          float4 g = g4[k];
          fe[4 * k + 0] = fmaf(wgt, g.x, fe[4 * k + 0]);
          fe[4 * k + 1] = fmaf(wgt, g.y, fe[4 * k + 1]);
          fe[4 * k + 2] = fmaf(wgt, g.z, fe[4 * k + 2]);
          fe[4 * k + 3] = fmaf(wgt, g.w, fe[4 * k + 3]);
        }
      }

  // feats -> bf16 -> X[t][0..31]  (wave-local rows; no barrier needed)
#pragma unroll
  for (int q = 0; q < 4; ++q) {
    s16x8 v;
#pragma unroll
    for (int j = 0; j < 8; ++j) v[j] = (short)f2bf(fe[q * 8 + j]);
    *(s16x8*)&s_X[tid * XPAD + q * 8] = v;
  }

  f32x4 acc[4][4];

  // ---- T1: 32 -> 64 (K=32, one k-step) ----
  {
    s16x8 a1[4];
#pragma unroll
    for (int mt = 0; mt < 4; ++mt)
      a1[mt] = *(const s16x8*)&s_X[(wrow + mt * 16 + ln15) * XPAD + quad * 8];
    float bv[4];
#pragma unroll
    for (int nt = 0; nt < 4; ++nt) bv[nt] = bt1[nt * 16 + ln15];
#pragma unroll
    for (int mt = 0; mt < 4; ++mt)
#pragma unroll
      for (int nt = 0; nt < 4; ++nt){ f32x4 c; c[0]=bv[nt];c[1]=bv[nt];c[2]=bv[nt];c[3]=bv[nt]; acc[mt][nt]=c; }
    s16x8 b[4];
#pragma unroll
    for (int nt = 0; nt < 4; ++nt)
      b[nt] = *(const s16x8*)(ws + (nt * 16 + ln15) * 32 + quad * 8);
#pragma unroll
    for (int mt = 0; mt < 4; ++mt)
#pragma unroll
      for (int nt = 0; nt < 4; ++nt)
        acc[mt][nt] = __builtin_amdgcn_mfma_f32_16x16x32_bf16(a1[mt], b[nt], acc[mt][nt], 0, 0, 0);
    store_relu(s_X, wrow, ln15, quad, acc);
  }

  // ---- T2: 64 -> 64 -> e ----
  {
    s16x8 a[4][2];
#pragma unroll
    for (int ks = 0; ks < 2; ++ks)
#pragma unroll
      for (int mt = 0; mt < 4; ++mt)
        a[mt][ks] = *(const s16x8*)&s_X[(wrow + mt * 16 + ln15) * XPAD + ks * 32 + quad * 8];
    layer64(a, ws + 2048, bt2, ln15, quad, acc);
    store_relu(s_X, wrow, ln15, quad, acc);   // X = e
  }

  // ---- keep e fragments in registers (A-operand layout) ----
  s16x8 ea[4][2];
#pragma unroll
  for (int ks = 0; ks < 2; ++ks)
#pragma unroll
    for (int mt = 0; mt < 4; ++mt)
      ea[mt][ks] = *(const s16x8*)&s_X[(wrow + mt * 16 + ln15) * XPAD + ks * 32 + quad * 8];

  // ---- opacity: relu(e@Wo1+bo1) -> X, then per-thread dot with Wo2 ----
  layer64(ea, ws + 6144, bo1, ln15, quad, acc);
  store_relu(s_X, wrow, ln15, quad, acc);
  float raw = bo2[0];
#pragma unroll
  for (int q = 0; q < 8; ++q) {
    s16x8 v = *(const s16x8*)&s_X[tid * XPAD + q * 8];
#pragma unroll
    for (int j = 0; j < 8; ++j)
      raw = fmaf(bf2f((unsigned short)v[j]), Wo2[q * 8 + j], raw);
  }
  const float density = softplusf_(raw);
  const float delta   = (fa - nr) * (1.0f / 128.0f);
  const float alpha   = 1.f - expf(-delta * density);

  __syncthreads();   // s_enc (cross-wave) ready

  // ---- color: cin-frags = e-frags + enc (enc varies only along k => per-wave broadcast frag) ----
  {
    s16x8 a[4][2];
#pragma unroll
    for (int ks = 0; ks < 2; ++ks) {
      const float* ep = &s_enc[r_loc][ks * 32 + quad * 8];
      float4 e0 = *(const float4*)ep;
      float4 e1 = *(const float4*)(ep + 4);
      float encv[8] = {e0.x, e0.y, e0.z, e0.w, e1.x, e1.y, e1.z, e1.w};
#pragma unroll
      for (int mt = 0; mt < 4; ++mt) {
        s16x8 v;
#pragma unroll
        for (int j = 0; j < 8; ++j)
          v[j] = (short)f2bf(bf2f((unsigned short)ea[mt][ks][j]) + encv[j]);
        a[mt][ks] = v;
      }
    }
    layer64(a, ws + 10240, bc1, ln15, quad, acc);
    store_relu(s_X, wrow, ln15, quad, acc);
  }
  float c0 = bc2[0], c1 = bc2[1], c2 = bc2[2];
#pragma unroll
  for (int q = 0; q < 8; ++q) {
    s16x8 v = *(const s16x8*)&s_X[tid * XPAD + q * 8];
#pragma unroll
    for (int j = 0; j < 8; ++j) {
      const float h = bf2f((unsigned short)v[j]);
      c0 = fmaf(h, Wc2[(q * 8 + j) * 3 + 0], c0);
      c1 = fmaf(h, Wc2[(q * 8 + j) * 3 + 1], c1);
      c2 = fmaf(h, Wc2[(q * 8 + j) * 3 + 2], c2);
    }
  }
  c0 = sigmoidf_(c0); c1 = sigmoidf_(c1); c2 = sigmoidf_(c2);

  // ---- transmittance scan (inclusive product of 1-alpha) ----
  float vv = 1.f - alpha;
  s_scan[r_loc][s_idx] = vv;
  __syncthreads();
#pragma unroll
  for (int off = 1; off < 128; off <<= 1) {
    const float u = (s_idx >= off) ? s_scan[r_loc][s_idx - off] : 1.f;
    __syncthreads();
    vv *= u;
    s_scan[r_loc][s_idx] = vv;
    __syncthreads();
  }
  const float Texcl = (s_idx == 0) ? 1.f : s_scan[r_loc][s_idx - 1];
  const float wgt = Texcl * alpha;

  // ---- color integral ----
  float p0 = wgt * c0, p1 = wgt * c1, p2 = wgt * c2;
#pragma unroll
  for (int off = 32; off > 0; off >>= 1) {
    p0 += __shfl_down(p0, off, 64);
    p1 += __shfl_down(p1, off, 64);
    p2 += __shfl_down(p2, off, 64);
  }
  if ((tid & 63) == 0) {
    const int wvi = s_idx >> 6;
    s_part[r_loc][wvi][0] = p0; s_part[r_loc][wvi][1] = p1; s_part[r_loc][wvi][2] = p2;
  }
  __syncthreads();
  if (s_idx == 0) {
    out[ray * 3 + 0] = s_part[r_loc][0][0] + s_part[r_loc][1][0];
    out[ray * 3 + 1] = s_part[r_loc][0][1] + s_part[r_loc][1][1];
    out[ray * 3 + 2] = s_part[r_loc][0][2] + s_part[r_loc][1][2];
    out[NRAYS * 3 + ray] = 1.f - s_scan[r_loc][127];
  }
}

extern "C" void kernel_launch(void* const* d_in, const int* in_sizes, int n_in,
                              void* d_out, int out_size, void* d_ws, size_t ws_size,
                              hipStream_t stream)
{
  (void)in_sizes; (void)n_in; (void)out_size; (void)ws_size;
  const float* origins = (const float*)d_in[0];
  const float* dirs    = (const float*)d_in[1];
  const float* nearv   = (const float*)d_in[2];
  const float* farv    = (const float*)d_in[3];
  const float* grid    = (const float*)d_in[4];
  const float* Wr  = (const float*)d_in[5];
  const float* br  = (const float*)d_in[6];
  const float* Wt1 = (const float*)d_in[7];
  const float* bt1 = (const float*)d_in[8];
  const float* Wt2 = (const float*)d_in[9];
  const float* bt2 = (const float*)d_in[10];
  const float* Wo1 = (const float*)d_in[11];
  const float* bo1 = (const float*)d_in[12];
  const float* Wo2 = (const float*)d_in[13];
  const float* bo2 = (const float*)d_in[14];
  const float* Wc1 = (const float*)d_in[15];
  const float* bc1 = (const float*)d_in[16];
  const float* Wc2 = (const float*)d_in[17];
  const float* bc2 = (const float*)d_in[18];
  unsigned short* ws = (unsigned short*)d_ws;
  float* out = (float*)d_out;

  prep_weights<<<16, 256, 0, stream>>>(Wt1, Wt2, Wo1, Wc1, ws);
  lightplane_fwd<<<NRAYS / 2, 256, 0, stream>>>(origins, dirs, nearv, farv, grid,
                                                Wr, br, bt1, bt2, bo1, Wo2, bo2,
                                                bc1, Wc2, bc2, ws, out);
}